// Round 2
// baseline (385.873 us; speedup 1.0000x reference)
//
#include <hip/hip_runtime.h>
#include <math.h>

#define FEAT 128

// ---------------- helpers ----------------

__device__ inline unsigned int pack_bf16(float a, float b) {
  unsigned int ua = __float_as_uint(a);
  unsigned int ub = __float_as_uint(b);
  ua = (ua + 0x7fffu + ((ua >> 16) & 1u)) >> 16;   // RNE
  ub = (ub + 0x7fffu + ((ub >> 16) & 1u)) >> 16;
  return ua | (ub << 16);
}

__device__ inline void acc8(float* acc, uint4 a) {
  acc[0] += __uint_as_float(a.x << 16);
  acc[1] += __uint_as_float(a.x & 0xffff0000u);
  acc[2] += __uint_as_float(a.y << 16);
  acc[3] += __uint_as_float(a.y & 0xffff0000u);
  acc[4] += __uint_as_float(a.z << 16);
  acc[5] += __uint_as_float(a.z & 0xffff0000u);
  acc[6] += __uint_as_float(a.w << 16);
  acc[7] += __uint_as_float(a.w & 0xffff0000u);
}

// ---------------- fused: mask gather+exp+partial-sum  |  degree count ----------------

__global__ void kA(const float* __restrict__ mask, const int* __restrict__ ids,
                   float* __restrict__ mv, float* __restrict__ pbuf, int ns,
                   const int* __restrict__ ed, int* __restrict__ deg, int ne, int gb) {
  if ((int)blockIdx.x < gb) {
    int i = blockIdx.x * 256 + threadIdx.x;
    float v = 0.f;
    if (i < ns) { v = expf(mask[ids[i]]); mv[i] = v; }
#pragma unroll
    for (int o = 32; o >= 1; o >>= 1) v += __shfl_xor(v, o, 64);
    __shared__ float s[4];
    if ((threadIdx.x & 63) == 0) s[threadIdx.x >> 6] = v;
    __syncthreads();
    if (threadIdx.x == 0) pbuf[blockIdx.x] = (s[0] + s[1]) + (s[2] + s[3]);
  } else {
    int i = ((blockIdx.x - gb) * 256 + threadIdx.x) * 4;
    if (i + 4 <= ne) {
      int4 e4 = *(const int4*)(ed + i);
      atomicAdd(&deg[e4.x], 1); atomicAdd(&deg[e4.y], 1);
      atomicAdd(&deg[e4.z], 1); atomicAdd(&deg[e4.w], 1);
    } else {
      for (int j = i; j < ne; j++) atomicAdd(&deg[ed[j]], 1);
    }
  }
}

__global__ void k_reduce_sum(const float* __restrict__ p, float* __restrict__ out, int n) {
  __shared__ float s[1024];
  float v = 0.f;
  for (int i = threadIdx.x; i < n; i += 1024) v += p[i];
  s[threadIdx.x] = v;
  __syncthreads();
  for (int o = 512; o >= 1; o >>= 1) {
    if (threadIdx.x < o) s[threadIdx.x] += s[threadIdx.x + o];
    __syncthreads();
  }
  if (threadIdx.x == 0) out[0] = 1.0f / s[0];   // inverse of softmax denominator
}

// ---------------- scan: deg -> rp (and cur = rp copy) ----------------

__global__ __launch_bounds__(1024) void k_scan(const int* __restrict__ cnt,
                                               int* __restrict__ rp, int* __restrict__ cur, int n) {
  __shared__ int wsum[16];
  __shared__ int cbase;
  int t = threadIdx.x, lane = t & 63, wid = t >> 6;
  if (t == 0) cbase = 0;
  __syncthreads();
  for (int base = 0; base < n; base += 8192) {
    int v[8];
    int tot = 0;
    int idx0 = base + t * 8;
#pragma unroll
    for (int j = 0; j < 8; j++) { int ix = idx0 + j; v[j] = (ix < n) ? cnt[ix] : 0; tot += v[j]; }
    int x = tot;
#pragma unroll
    for (int o = 1; o < 64; o <<= 1) { int y = __shfl_up(x, o, 64); if (lane >= o) x += y; }
    if (lane == 63) wsum[wid] = x;
    __syncthreads();
    if (t < 16) {
      int w = wsum[t];
#pragma unroll
      for (int o = 1; o < 16; o <<= 1) { int y = __shfl_up(w, o, 64); if (t >= o) w += y; }
      wsum[t] = w;
    }
    __syncthreads();
    int wexcl = (wid == 0) ? 0 : wsum[wid - 1];
    int run = cbase + wexcl + (x - tot);
#pragma unroll
    for (int j = 0; j < 8; j++) {
      int ix = idx0 + j;
      if (ix < n) { rp[ix] = run; cur[ix] = run; }
      run += v[j];
    }
    __syncthreads();
    if (t == 0) cbase += wsum[15];
    __syncthreads();
  }
  if (t == 0) rp[n] = cbase;
}

// ---------------- normalize mv + build bf16 pre-scaled feature table ----------------

__global__ __launch_bounds__(256) void k_scale(const float* __restrict__ h,
                                               float* __restrict__ mv, const float* __restrict__ ginv,
                                               unsigned int* __restrict__ hs, int ns) {
  int row = blockIdx.x * 8 + (threadIdx.x >> 5);
  if (row >= ns) return;
  int c = (threadIdx.x & 31) * 4;
  float m = mv[row] * ginv[0];
  float4 v = *(const float4*)(h + (size_t)row * FEAT + c);
  unsigned int u0 = pack_bf16(v.x * m, v.y * m);
  unsigned int u1 = pack_bf16(v.z * m, v.w * m);
  *(uint2*)(hs + (size_t)row * 64 + (c >> 1)) = make_uint2(u0, u1);
  if ((threadIdx.x & 31) == 0) mv[row] = m;
}

__global__ void k_norm(float* __restrict__ mv, const float* __restrict__ ginv, int n) {
  int i = blockIdx.x * 256 + threadIdx.x;
  if (i < n) mv[i] *= ginv[0];
}

// ---------------- scatter: fill CSR ----------------

__global__ void k_scatter(const int* __restrict__ es, const int* __restrict__ ed,
                          int* __restrict__ cur, int* __restrict__ csr, int ne) {
  int i = (blockIdx.x * 256 + threadIdx.x) * 4;
  if (i + 4 <= ne) {
    int4 s4 = *(const int4*)(es + i);
    int4 d4 = *(const int4*)(ed + i);
    csr[atomicAdd(&cur[d4.x], 1)] = s4.x;
    csr[atomicAdd(&cur[d4.y], 1)] = s4.y;
    csr[atomicAdd(&cur[d4.z], 1)] = s4.z;
    csr[atomicAdd(&cur[d4.w], 1)] = s4.w;
  } else {
    for (int j = i; j < ne; j++) csr[atomicAdd(&cur[ed[j]], 1)] = es[j];
  }
}

// ---------------- aggregation: bf16 gather, 4 edges per wave pass ----------------

__global__ __launch_bounds__(64) void k_agg_bf(const int* __restrict__ rp, const int* __restrict__ csr,
                                               const unsigned int* __restrict__ hs,
                                               float* __restrict__ out) {
  int d = blockIdx.x;
  int beg = rp[d], end = rp[d + 1];
  int lane = threadIdx.x;
  int q = lane >> 4;           // edge slot 0..3
  int fw = (lane & 15) * 4;    // u32 offset within 64-u32 row
  float acc[8] = {0, 0, 0, 0, 0, 0, 0, 0};
  int e = beg;
  for (; e + 8 <= end; e += 8) {
    int s0 = csr[e + q];
    int s1 = csr[e + 4 + q];
    uint4 a = *(const uint4*)(hs + (size_t)s0 * 64 + fw);
    uint4 b = *(const uint4*)(hs + (size_t)s1 * 64 + fw);
    acc8(acc, a);
    acc8(acc, b);
  }
  if (e + 4 <= end) {
    int s0 = csr[e + q];
    uint4 a = *(const uint4*)(hs + (size_t)s0 * 64 + fw);
    acc8(acc, a);
    e += 4;
  }
  int rem = end - e;
  if (q < rem) {
    int s0 = csr[e + q];
    uint4 a = *(const uint4*)(hs + (size_t)s0 * 64 + fw);
    acc8(acc, a);
  }
#pragma unroll
  for (int j = 0; j < 8; j++) {
    acc[j] += __shfl_xor(acc[j], 16, 64);
    acc[j] += __shfl_xor(acc[j], 32, 64);
  }
  if (lane < 16) {
    float inv = 1.0f / fmaxf((float)(end - beg), 1.0f);
    float4 o0 = make_float4(acc[0] * inv, acc[1] * inv, acc[2] * inv, acc[3] * inv);
    float4 o1 = make_float4(acc[4] * inv, acc[5] * inv, acc[6] * inv, acc[7] * inv);
    float* p = out + (size_t)d * FEAT + fw * 2;
    *(float4*)p = o0;
    *(float4*)(p + 4) = o1;
  }
}

// fallback f32 aggregation (if workspace too small for hs)
__global__ __launch_bounds__(64) void k_agg_f32(const int* __restrict__ rp, const int* __restrict__ csr,
                                                const float* __restrict__ h, const float* __restrict__ mv,
                                                float* __restrict__ rst) {
  int d = blockIdx.x;
  int beg = rp[d], end = rp[d + 1];
  int lane = threadIdx.x;
  float ax = 0.f, ay = 0.f;
  int e = beg;
  for (; e + 4 <= end; e += 4) {
    int s0 = csr[e + 0], s1 = csr[e + 1], s2 = csr[e + 2], s3 = csr[e + 3];
    float m0 = mv[s0], m1 = mv[s1], m2 = mv[s2], m3 = mv[s3];
    float2 v0 = *(const float2*)(h + (size_t)s0 * FEAT + lane * 2);
    float2 v1 = *(const float2*)(h + (size_t)s1 * FEAT + lane * 2);
    float2 v2 = *(const float2*)(h + (size_t)s2 * FEAT + lane * 2);
    float2 v3 = *(const float2*)(h + (size_t)s3 * FEAT + lane * 2);
    ax += v0.x * m0; ay += v0.y * m0;
    ax += v1.x * m1; ay += v1.y * m1;
    ax += v2.x * m2; ay += v2.y * m2;
    ax += v3.x * m3; ay += v3.y * m3;
  }
  for (; e < end; ++e) {
    int s = csr[e];
    float m = mv[s];
    float2 v = *(const float2*)(h + (size_t)s * FEAT + lane * 2);
    ax += v.x * m; ay += v.y * m;
  }
  float inv = 1.0f / fmaxf((float)(end - beg), 1.0f);
  float2 o;
  o.x = ax * inv;
  o.y = ay * inv;
  *(float2*)(rst + (size_t)d * FEAT + lane * 2) = o;
}

// ---------------- in-place dense transform: out = rst @ W + b ----------------

__global__ __launch_bounds__(256) void k_gemm(float* __restrict__ out, const float* __restrict__ W,
                                              const float* __restrict__ b, int nd) {
  __shared__ float Ws[FEAT * FEAT];   // 64 KiB
  __shared__ float Rs[32][FEAT];      // 16 KiB
  int t = threadIdx.x;
  for (int i = t * 4; i < FEAT * FEAT; i += 1024) *(float4*)(Ws + i) = *(const float4*)(W + i);
  int c0 = (t & 31) * 4;
  int rg = (t >> 5) * 4;
  float4 bb = *(const float4*)(b + c0);
  for (int ch = 0; ch < 4; ch++) {
    int r0 = blockIdx.x * 128 + ch * 32;
    if (r0 >= nd) break;
    int rows = min(32, nd - r0);
    __syncthreads();   // Ws ready / previous chunk's reads done
    for (int i = t; i < rows * FEAT; i += 256) Rs[i >> 7][i & 127] = out[(size_t)r0 * FEAT + i];
    __syncthreads();
    float acc[4][4];
#pragma unroll
    for (int i = 0; i < 4; i++) { acc[i][0] = bb.x; acc[i][1] = bb.y; acc[i][2] = bb.z; acc[i][3] = bb.w; }
    for (int k = 0; k < FEAT; k += 4) {
#pragma unroll
      for (int kk = 0; kk < 4; kk++) {
        float4 wv = *(const float4*)(&Ws[(k + kk) * FEAT + c0]);
#pragma unroll
        for (int i = 0; i < 4; i++) {
          float rv = Rs[rg + i][k + kk];
          acc[i][0] += rv * wv.x;
          acc[i][1] += rv * wv.y;
          acc[i][2] += rv * wv.z;
          acc[i][3] += rv * wv.w;
        }
      }
    }
#pragma unroll
    for (int i = 0; i < 4; i++) {
      int r = rg + i;
      if (r < rows) *(float4*)(out + (size_t)(r0 + r) * FEAT + c0) = *(float4*)acc[i];
    }
  }
}

// ---------------- launcher ----------------

extern "C" void kernel_launch(void* const* d_in, const int* in_sizes, int n_in,
                              void* d_out, int out_size, void* d_ws, size_t ws_size,
                              hipStream_t stream) {
  const float* h    = (const float*)d_in[0];
  const int*   ids  = (const int*)d_in[1];
  const int*   es   = (const int*)d_in[2];
  const int*   ed   = (const int*)d_in[3];
  const float* mask = (const float*)d_in[4];
  const float* W    = (const float*)d_in[5];
  const float* b    = (const float*)d_in[6];
  float* out = (float*)d_out;

  const int NS = in_sizes[1];
  const int E  = in_sizes[2];
  const int H  = in_sizes[6];
  const int ND = (out_size - NS) / H;

  float* mv = out + (size_t)ND * H;   // mask_values output doubles as scratch

  char* w = (char*)d_ws;
  size_t used = 0;
  auto carve = [&](size_t bytes) -> char* {
    char* p = w + used;
    used += (bytes + 255) & ~(size_t)255;
    return p;
  };
  float* pbuf = (float*)carve(4096 * sizeof(float));
  float* ginv = (float*)carve(256);
  int* deg = (int*)carve((size_t)ND * sizeof(int));
  int* cur = (int*)carve((size_t)ND * sizeof(int));
  int* rp  = (int*)carve((size_t)(ND + 1) * sizeof(int));
  int* csr = (int*)carve((size_t)E * sizeof(int));
  size_t hs_bytes = (size_t)NS * FEAT * 2;
  unsigned int* hs = nullptr;
  if (used + hs_bytes + 256 <= ws_size) hs = (unsigned int*)carve(hs_bytes);

  hipMemsetAsync(deg, 0, (size_t)ND * sizeof(int), stream);

  const int gb = (NS + 255) / 256;
  const int db = ((E + 3) / 4 + 255) / 256;

  kA<<<gb + db, 256, 0, stream>>>(mask, ids, mv, pbuf, NS, ed, deg, E, gb);
  k_reduce_sum<<<1, 1024, 0, stream>>>(pbuf, ginv, gb);
  k_scan<<<1, 1024, 0, stream>>>(deg, rp, cur, ND);
  if (hs) k_scale<<<(NS + 7) / 8, 256, 0, stream>>>(h, mv, ginv, hs, NS);
  else    k_norm<<<(NS + 255) / 256, 256, 0, stream>>>(mv, ginv, NS);
  k_scatter<<<db, 256, 0, stream>>>(es, ed, cur, csr, E);
  if (hs) k_agg_bf<<<ND, 64, 0, stream>>>(rp, csr, hs, out);
  else    k_agg_f32<<<ND, 64, 0, stream>>>(rp, csr, h, mv, out);
  k_gemm<<<(ND + 127) / 128, 256, 0, stream>>>(out, W, b, ND);
}